// Round 13
// baseline (104.923 us; speedup 1.0000x reference)
//
#include <hip/hip_runtime.h>

#define NEG 0.2f
#define CAP 6144        // bucket capacity; mean 4096, +32 sigma safety
#define EPB 2048        // edges per scatter block

__device__ __forceinline__ float leaky(float v){ return fmaxf(v, NEG * v); }

// order-preserving float<->uint map for atomicMax on floats
__device__ __forceinline__ unsigned fmap(float f){
    unsigned b = __float_as_uint(f);
    return (b & 0x80000000u) ? ~b : (b | 0x80000000u);
}
__device__ __forceinline__ float funmap(unsigned u){
    return (u & 0x80000000u) ? __uint_as_float(u & 0x7fffffffu) : __uint_as_float(~u);
}

// seed per-bucket global cursors at b*CAP
__global__ void __launch_bounds__(256) k_init(int* __restrict__ gcur, int nb){
    int t = blockIdx.x * 256 + threadIdx.x;
    if (t < nb) gcur[t] = t * CAP;
}

// ---------------------------------------------------------------------------
// k_scatter: per block of 2048 edges, LDS histogram of bucket = dst>>8, ONE
// global atomicAdd per (block,bucket) to reserve a contiguous run, then
// scatter 16B records {xs, xd, a, dst&255}. Each block's bucket members land
// consecutively -> coalesced sectors instead of per-edge scattered RMWs.
// ---------------------------------------------------------------------------
__global__ void __launch_bounds__(256) k_scatter(
        const int* __restrict__ src, const int* __restrict__ dst,
        const float* __restrict__ attr, const float* __restrict__ x,
        int* __restrict__ gcur, float4* __restrict__ sorted, int E, int nb){
    __shared__ int hist[256];
    __shared__ int cur[256];
    const int tid = threadIdx.x;
    for (int k = tid; k < nb; k += 256) hist[k] = 0;
    __syncthreads();
    const int base = blockIdx.x * EPB;
    const int lim  = min(EPB, E - base);
    for (int k = tid; k < lim; k += 256)
        atomicAdd(&hist[dst[base + k] >> 8], 1);       // LDS
    __syncthreads();
    for (int k = tid; k < nb; k += 256){
        int c = hist[k];
        cur[k] = c ? atomicAdd(&gcur[k], c) : 0;       // global, aggregated
    }
    __syncthreads();
    for (int k = tid; k < lim; k += 256){
        int e = base + k;
        int d = dst[e];
        int b = d >> 8;
        int pos = atomicAdd(&cur[b], 1);               // LDS; global slot (seeded)
        if (pos < (b + 1) * CAP)
            sorted[pos] = make_float4(x[src[e]], x[d], attr[e],
                                      __int_as_float(d & 255));
    }
}

// ---------------------------------------------------------------------------
// k_node: one 1024-thread block per bucket (256 consecutive nodes).
// Phase A: r12's verified 16-lane/16-edge register-weight logit loop over the
//   bucket's coalesced records; exact per-node max via LDS atomicMax.
// Phase B: p = exp(l - m); LDS atomicAdd of denom/numer/asum/deg.
// Epilogue: r12's verified 16-lane self-loop logit + fold + rank-1 row write,
//   reading the reduced state from LDS. 4 passes x 64 nodes.
// ---------------------------------------------------------------------------
__global__ void __launch_bounds__(1024) k_node(
        const float* __restrict__ x,
        const int* __restrict__ gcur, const float4* __restrict__ sorted,
        const float* __restrict__ Wl, const float* __restrict__ Wr,
        const float* __restrict__ We, const float* __restrict__ bl,
        const float* __restrict__ br, const float* __restrict__ att,
        const float* __restrict__ bias,
        float4* __restrict__ out, int N){
    __shared__ unsigned mm[256][2];
    __shared__ float    dd[256][2];
    __shared__ float    nn[256][2];
    __shared__ float    as_[256];
    __shared__ int      dg[256];
    const int tid = threadIdx.x;
    const int b   = blockIdx.x;
    if (tid < 256){
        mm[tid][0] = 0u;  mm[tid][1] = 0u;      // fmap(-inf) < any mapped value
        dd[tid][0] = 0.f; dd[tid][1] = 0.f;
        nn[tid][0] = 0.f; nn[tid][1] = 0.f;
        as_[tid] = 0.f;   dg[tid] = 0;
    }

    // 16-lane register weight preload (r12 layout): lane ln owns ch ln*8..+7
    const int ln = tid & 15;
    const float4* Wl4 = (const float4*)Wl;
    const float4* Wr4 = (const float4*)Wr;
    const float4* We4 = (const float4*)We;
    const float4* bl4 = (const float4*)bl;
    const float4* br4 = (const float4*)br;
    const float4* at4 = (const float4*)att;
    const int q = ln * 2;
    float4 wl0 = Wl4[q], wl1 = Wl4[q+1];
    float4 wr0 = Wr4[q], wr1 = Wr4[q+1];
    float4 we0 = We4[q], we1 = We4[q+1];
    float4 b0  = bl4[q], b1  = bl4[q+1];
    float4 c0  = br4[q], c1  = br4[q+1];
    float4 a0  = at4[q], a1  = at4[q+1];
    b0.x += c0.x; b0.y += c0.y; b0.z += c0.z; b0.w += c0.w;
    b1.x += c1.x; b1.y += c1.y; b1.z += c1.z; b1.w += c1.w;
    __syncthreads();

    int cnt = gcur[b] - b * CAP;
    if (cnt > CAP) cnt = CAP;
    const float4* bucket = sorted + (size_t)b * CAP;

    // ---- phase A: logits + LDS atomicMax; stash for phase B ----
    float l0s[6], l1s[6], xss[6], aas[6];
    int   nds[6];
    #pragma unroll
    for (int p = 0; p < 6; ++p){
        int idx = p * 1024 + tid;
        bool val = idx < cnt;
        float4 f4 = val ? bucket[idx] : make_float4(0.f, 0.f, 0.f, 0.f);
        float xsL = f4.x, xdL = f4.y, aL = f4.z;
        int node = val ? (__float_as_int(f4.w) & 255) : -1;
        float l0L = 0.f, l1L = 0.f;
        for (int j = 0; j < 16; ++j){
            float xs = __shfl(xsL, j, 16);
            float xd = __shfl(xdL, j, 16);
            float a  = __shfl(aL,  j, 16);
            float acc;
            {
                float v0 = fmaf(xs, wl0.x, fmaf(xd, wr0.x, fmaf(a, we0.x, b0.x)));
                float v1 = fmaf(xs, wl0.y, fmaf(xd, wr0.y, fmaf(a, we0.y, b0.y)));
                float v2 = fmaf(xs, wl0.z, fmaf(xd, wr0.z, fmaf(a, we0.z, b0.z)));
                float v3 = fmaf(xs, wl0.w, fmaf(xd, wr0.w, fmaf(a, we0.w, b0.w)));
                acc  = leaky(v0) * a0.x;
                acc  = fmaf(leaky(v1), a0.y, acc);
                acc  = fmaf(leaky(v2), a0.z, acc);
                acc  = fmaf(leaky(v3), a0.w, acc);
                v0 = fmaf(xs, wl1.x, fmaf(xd, wr1.x, fmaf(a, we1.x, b1.x)));
                v1 = fmaf(xs, wl1.y, fmaf(xd, wr1.y, fmaf(a, we1.y, b1.y)));
                v2 = fmaf(xs, wl1.z, fmaf(xd, wr1.z, fmaf(a, we1.z, b1.z)));
                v3 = fmaf(xs, wl1.w, fmaf(xd, wr1.w, fmaf(a, we1.w, b1.w)));
                acc  = fmaf(leaky(v0), a1.x, acc);
                acc  = fmaf(leaky(v1), a1.y, acc);
                acc  = fmaf(leaky(v2), a1.z, acc);
                acc  = fmaf(leaky(v3), a1.w, acc);
            }
            acc += __shfl_xor(acc, 1);
            acc += __shfl_xor(acc, 2);
            acc += __shfl_xor(acc, 4);
            float other = __shfl_xor(acc, 8);
            if (ln == j){
                l0L = (j < 8) ? acc : other;
                l1L = (j < 8) ? other : acc;
            }
        }
        if (val){
            atomicMax(&mm[node][0], fmap(l0L));
            atomicMax(&mm[node][1], fmap(l1L));
        }
        l0s[p] = l0L; l1s[p] = l1L; xss[p] = xsL; aas[p] = aL; nds[p] = node;
    }
    __syncthreads();

    // ---- phase B: exp + LDS accumulate ----
    #pragma unroll
    for (int p = 0; p < 6; ++p){
        int node = nds[p];
        if (node >= 0){
            float m0 = funmap(mm[node][0]);
            float m1 = funmap(mm[node][1]);
            float p0 = __expf(l0s[p] - m0);
            float p1 = __expf(l1s[p] - m1);
            atomicAdd(&dd[node][0], p0);
            atomicAdd(&nn[node][0], p0 * xss[p]);
            atomicAdd(&dd[node][1], p1);
            atomicAdd(&nn[node][1], p1 * xss[p]);
            atomicAdd(&as_[node], aas[p]);
            atomicAdd(&dg[node], 1);
        }
    }
    __syncthreads();

    // ---- epilogue: 4 passes x 64 nodes; 16 lanes per node (r12 verbatim) ----
    const int grp = tid >> 4;           // 0..63
    float4 ww0 = Wl4[ln],  ww1 = Wl4[ln + 16];
    float4 gg0 = bl4[ln],  gg1 = bl4[ln + 16];
    float4 z0  = ((const float4*)bias)[ln], z1 = ((const float4*)bias)[ln + 16];
    #pragma unroll
    for (int qq = 0; qq < 4; ++qq){
        int node = qq * 64 + grp;
        int i = b * 256 + node;
        if (i >= N) continue;
        int   degv = dg[node];
        float m0 = degv ? funmap(mm[node][0]) : -3.4e38f;
        float m1 = degv ? funmap(mm[node][1]) : -3.4e38f;
        float d0 = dd[node][0], n0 = nn[node][0];
        float d1 = dd[node][1], n1 = nn[node][1];
        float la = as_[node] / (float)max(degv, 1);
        float xi = x[i];
        // self-loop logit, 8 channels per lane: v = xi*(wl+wr) + la*we + bsum
        float pl;
        {
            float v0 = fmaf(xi, wl0.x + wr0.x, fmaf(la, we0.x, b0.x));
            float v1 = fmaf(xi, wl0.y + wr0.y, fmaf(la, we0.y, b0.y));
            float v2 = fmaf(xi, wl0.z + wr0.z, fmaf(la, we0.z, b0.z));
            float v3 = fmaf(xi, wl0.w + wr0.w, fmaf(la, we0.w, b0.w));
            pl  = leaky(v0) * a0.x;
            pl  = fmaf(leaky(v1), a0.y, pl);
            pl  = fmaf(leaky(v2), a0.z, pl);
            pl  = fmaf(leaky(v3), a0.w, pl);
            v0 = fmaf(xi, wl1.x + wr1.x, fmaf(la, we1.x, b1.x));
            v1 = fmaf(xi, wl1.y + wr1.y, fmaf(la, we1.y, b1.y));
            v2 = fmaf(xi, wl1.z + wr1.z, fmaf(la, we1.z, b1.z));
            v3 = fmaf(xi, wl1.w + wr1.w, fmaf(la, we1.w, b1.w));
            pl  = fmaf(leaky(v0), a1.x, pl);
            pl  = fmaf(leaky(v1), a1.y, pl);
            pl  = fmaf(leaky(v2), a1.z, pl);
            pl  = fmaf(leaky(v3), a1.w, pl);
        }
        pl += __shfl_xor(pl, 1);
        pl += __shfl_xor(pl, 2);
        pl += __shfl_xor(pl, 4);
        float other = __shfl_xor(pl, 8);
        float l0 = (ln < 8) ? pl : other;
        float l1 = (ln < 8) ? other : pl;
        {
            float mn = fmaxf(m0, l0);
            float s = __expf(m0 - mn), p = __expf(l0 - mn);
            d0 = fmaf(d0, s, p);
            n0 = fmaf(n0, s, p * xi);
        }
        {
            float mn = fmaxf(m1, l1);
            float s = __expf(m1 - mn), p = __expf(l1 - mn);
            d1 = fmaf(d1, s, p);
            n1 = fmaf(n1, s, p * xi);
        }
        float sres0 = n0 / d0;
        float sres1 = n1 / d1;
        float4* orow = out + (size_t)i * 32;
        orow[ln]      = make_float4(fmaf(sres0, ww0.x, gg0.x + z0.x),
                                    fmaf(sres0, ww0.y, gg0.y + z0.y),
                                    fmaf(sres0, ww0.z, gg0.z + z0.z),
                                    fmaf(sres0, ww0.w, gg0.w + z0.w));
        orow[ln + 16] = make_float4(fmaf(sres1, ww1.x, gg1.x + z1.x),
                                    fmaf(sres1, ww1.y, gg1.y + z1.y),
                                    fmaf(sres1, ww1.z, gg1.z + z1.z),
                                    fmaf(sres1, ww1.w, gg1.w + z1.w));
    }
}

extern "C" void kernel_launch(void* const* d_in, const int* in_sizes, int n_in,
                              void* d_out, int out_size, void* d_ws, size_t ws_size,
                              hipStream_t stream) {
    const float* x    = (const float*)d_in[0];
    const int*   ei   = (const int*)  d_in[1];
    const float* attr = (const float*)d_in[2];
    const float* Wl   = (const float*)d_in[3];
    const float* bl   = (const float*)d_in[4];
    const float* Wr   = (const float*)d_in[5];
    const float* br   = (const float*)d_in[6];
    const float* We   = (const float*)d_in[7];
    const float* att  = (const float*)d_in[8];
    const float* bias = (const float*)d_in[9];
    float* out = (float*)d_out;

    const int N = in_sizes[0];       // 50000
    const int E = in_sizes[2];       // 800000
    const int* src = ei;
    const int* dst = ei + E;

    const int nb = (N + 255) >> 8;   // 196 buckets of 256 nodes

    // workspace: sorted [nb*CAP]float4 (~19.3 MB) | gcur [nb]int
    char* w = (char*)d_ws;
    float4* sorted = (float4*)w;
    int*    gcur   = (int*)(w + (size_t)nb * CAP * 16);

    k_init<<<(nb + 255) / 256, 256, 0, stream>>>(gcur, nb);
    k_scatter<<<(E + EPB - 1) / EPB, 256, 0, stream>>>(src, dst, attr, x,
                                                       gcur, sorted, E, nb);
    k_node<<<nb, 1024, 0, stream>>>(x, gcur, sorted,
                                    Wl, Wr, We, bl, br, att, bias,
                                    (float4*)out, N);
}

// Round 14
// 93.448 us; speedup vs baseline: 1.1228x; 1.1228x over previous
//
#include <hip/hip_runtime.h>

#define NEG 0.2f
#define BN  128         // nodes per bucket
#define CAP 3072        // bucket capacity; mean ~2048, +22 sigma safety
#define EPB 2048        // edges per scatter block

__device__ __forceinline__ float leaky(float v){ return fmaxf(v, NEG * v); }

// order-preserving float<->uint map for atomicMax on floats
__device__ __forceinline__ unsigned fmap(float f){
    unsigned b = __float_as_uint(f);
    return (b & 0x80000000u) ? ~b : (b | 0x80000000u);
}
__device__ __forceinline__ float funmap(unsigned u){
    return (u & 0x80000000u) ? __uint_as_float(u & 0x7fffffffu) : __uint_as_float(~u);
}

// seed per-bucket global cursors at b*CAP
__global__ void __launch_bounds__(256) k_init(int* __restrict__ gcur, int nb){
    int t = blockIdx.x * 256 + threadIdx.x;
    if (t < nb) gcur[t] = t * CAP;
}

// ---------------------------------------------------------------------------
// k_scatter: per block of 2048 edges, LDS histogram of bucket = dst>>7, ONE
// global atomicAdd per (block,bucket) to reserve a contiguous run, then
// scatter 16B records {xs, xd, a, dst&127}. Block's bucket members land
// consecutively -> mostly-coalesced sectors; ~150k aggregated global atomics
// total instead of 800k scattered RMWs.
// ---------------------------------------------------------------------------
__global__ void __launch_bounds__(256) k_scatter(
        const int* __restrict__ src, const int* __restrict__ dst,
        const float* __restrict__ attr, const float* __restrict__ x,
        int* __restrict__ gcur, float4* __restrict__ sorted, int E, int nb){
    __shared__ int hist[512];
    __shared__ int cur[512];
    const int tid = threadIdx.x;
    for (int k = tid; k < nb; k += 256) hist[k] = 0;
    __syncthreads();
    const int base = blockIdx.x * EPB;
    const int lim  = min(EPB, E - base);
    for (int k = tid; k < lim; k += 256)
        atomicAdd(&hist[dst[base + k] >> 7], 1);       // LDS
    __syncthreads();
    for (int k = tid; k < nb; k += 256){
        int c = hist[k];
        cur[k] = c ? atomicAdd(&gcur[k], c) : 0;       // global, aggregated
    }
    __syncthreads();
    for (int k = tid; k < lim; k += 256){
        int e = base + k;
        int d = dst[e];
        int b = d >> 7;
        int pos = atomicAdd(&cur[b], 1);               // LDS; global slot (seeded)
        if (pos < (b + 1) * CAP)
            sorted[pos] = make_float4(x[src[e]], x[d], attr[e],
                                      __int_as_float(d & (BN - 1)));
    }
}

// ---------------------------------------------------------------------------
// k_node: one 1024-thread block per 128-node bucket.
// Phase A: one THREAD per edge; both head logits via LDS weight table pk[]
//   (uniform index -> broadcast reads, no shfl, no divergence); store logits
//   to lg[][2] in LDS; exact per-node max via LDS atomicMax.
// Phase B: re-read bucket (L1/L2-hot) + lg; p = exp(l-m); LDS atomicAdd.
// Epilogue: 16 lanes/node, lane ln owns channels k*16+ln (conflict-free pk
//   reads); shfl reduce; fold self-loop; fused rank-1 row write.
// ---------------------------------------------------------------------------
__global__ void __launch_bounds__(1024) k_node(
        const float* __restrict__ x,
        const int* __restrict__ gcur, const float4* __restrict__ sorted,
        const float* __restrict__ Wl, const float* __restrict__ Wr,
        const float* __restrict__ We, const float* __restrict__ bl,
        const float* __restrict__ br, const float* __restrict__ att,
        const float* __restrict__ bias,
        float4* __restrict__ out, int N){
    __shared__ float4   pk[128];        // {Wl, Wr, We, bl+br}
    __shared__ float    pat[128];       // att
    __shared__ float    lg[CAP][2];
    __shared__ unsigned mm[BN][2];
    __shared__ float    dd[BN][2];
    __shared__ float    nn[BN][2];
    __shared__ float    as_[BN];
    __shared__ int      dg[BN];
    const int tid = threadIdx.x;
    const int b   = blockIdx.x;
    if (tid < 128){
        pk[tid] = make_float4(Wl[tid], Wr[tid], We[tid], bl[tid] + br[tid]);
        pat[tid] = att[tid];
        mm[tid & (BN-1)][0] = 0u; mm[tid & (BN-1)][1] = 0u;
        dd[tid & (BN-1)][0] = 0.f; dd[tid & (BN-1)][1] = 0.f;
        nn[tid & (BN-1)][0] = 0.f; nn[tid & (BN-1)][1] = 0.f;
        as_[tid & (BN-1)] = 0.f; dg[tid & (BN-1)] = 0;
    }
    __syncthreads();

    int cnt = gcur[b] - b * CAP;
    if (cnt > CAP) cnt = CAP;
    const float4* bucket = sorted + (size_t)b * CAP;

    // ---- phase A: per-edge logits (broadcast pk reads) + LDS atomicMax ----
    for (int idx = tid; idx < cnt; idx += 1024){
        float4 f4 = bucket[idx];
        float xs = f4.x, xd = f4.y, a = f4.z;
        int node = __float_as_int(f4.w) & (BN - 1);
        float l0 = 0.f, l1 = 0.f;
        #pragma unroll 16
        for (int c = 0; c < 64; ++c){
            float4 p = pk[c];
            float v = fmaf(xs, p.x, fmaf(xd, p.y, fmaf(a, p.z, p.w)));
            l0 = fmaf(leaky(v), pat[c], l0);
        }
        #pragma unroll 16
        for (int c = 64; c < 128; ++c){
            float4 p = pk[c];
            float v = fmaf(xs, p.x, fmaf(xd, p.y, fmaf(a, p.z, p.w)));
            l1 = fmaf(leaky(v), pat[c], l1);
        }
        lg[idx][0] = l0;
        lg[idx][1] = l1;
        atomicMax(&mm[node][0], fmap(l0));
        atomicMax(&mm[node][1], fmap(l1));
    }
    __syncthreads();

    // ---- phase B: exp + LDS accumulate ----
    for (int idx = tid; idx < cnt; idx += 1024){
        float4 f4 = bucket[idx];
        int node = __float_as_int(f4.w) & (BN - 1);
        float p0 = __expf(lg[idx][0] - funmap(mm[node][0]));
        float p1 = __expf(lg[idx][1] - funmap(mm[node][1]));
        atomicAdd(&dd[node][0], p0);
        atomicAdd(&nn[node][0], p0 * f4.x);
        atomicAdd(&dd[node][1], p1);
        atomicAdd(&nn[node][1], p1 * f4.x);
        atomicAdd(&as_[node], f4.z);
        atomicAdd(&dg[node], 1);
    }
    __syncthreads();

    // ---- epilogue: 2 rounds x 64 nodes; 16 lanes per node ----
    const int ln  = tid & 15;
    const int grp = tid >> 4;           // 0..63
    const float4* Wl4 = (const float4*)Wl;
    const float4* bl4 = (const float4*)bl;
    const float4* bs4 = (const float4*)bias;
    float4 ww0 = Wl4[ln],  ww1 = Wl4[ln + 16];
    float4 gg0 = bl4[ln],  gg1 = bl4[ln + 16];
    float4 z0  = bs4[ln],  z1  = bs4[ln + 16];
    #pragma unroll
    for (int r = 0; r < 2; ++r){
        int node = r * 64 + grp;
        int i = b * BN + node;
        if (i >= N) continue;
        int   degv = dg[node];
        float m0 = degv ? funmap(mm[node][0]) : -3.4e38f;
        float m1 = degv ? funmap(mm[node][1]) : -3.4e38f;
        float d0 = dd[node][0], n0 = nn[node][0];
        float d1 = dd[node][1], n1 = nn[node][1];
        float la = as_[node] / (float)max(degv, 1);
        float xi = x[i];
        // self-loop logit: lane ln owns channels k*16+ln (k=0..3 -> head0,
        // k=4..7 -> head1); v = xi*(Wl+Wr) + la*We + (bl+br)
        float pl0 = 0.f, pl1 = 0.f;
        #pragma unroll
        for (int k = 0; k < 4; ++k){
            int c = k * 16 + ln;
            float4 p = pk[c];
            float v = fmaf(xi, p.x + p.y, fmaf(la, p.z, p.w));
            pl0 = fmaf(leaky(v), pat[c], pl0);
        }
        #pragma unroll
        for (int k = 4; k < 8; ++k){
            int c = k * 16 + ln;
            float4 p = pk[c];
            float v = fmaf(xi, p.x + p.y, fmaf(la, p.z, p.w));
            pl1 = fmaf(leaky(v), pat[c], pl1);
        }
        pl0 += __shfl_xor(pl0, 1); pl1 += __shfl_xor(pl1, 1);
        pl0 += __shfl_xor(pl0, 2); pl1 += __shfl_xor(pl1, 2);
        pl0 += __shfl_xor(pl0, 4); pl1 += __shfl_xor(pl1, 4);
        pl0 += __shfl_xor(pl0, 8); pl1 += __shfl_xor(pl1, 8);
        // fold self-loop into reduced softmax state
        {
            float mn = fmaxf(m0, pl0);
            float s = __expf(m0 - mn), p = __expf(pl0 - mn);
            d0 = fmaf(d0, s, p);
            n0 = fmaf(n0, s, p * xi);
        }
        {
            float mn = fmaxf(m1, pl1);
            float s = __expf(m1 - mn), p = __expf(pl1 - mn);
            d1 = fmaf(d1, s, p);
            n1 = fmaf(n1, s, p * xi);
        }
        float sres0 = n0 / d0;
        float sres1 = n1 / d1;
        float4* orow = out + (size_t)i * 32;
        orow[ln]      = make_float4(fmaf(sres0, ww0.x, gg0.x + z0.x),
                                    fmaf(sres0, ww0.y, gg0.y + z0.y),
                                    fmaf(sres0, ww0.z, gg0.z + z0.z),
                                    fmaf(sres0, ww0.w, gg0.w + z0.w));
        orow[ln + 16] = make_float4(fmaf(sres1, ww1.x, gg1.x + z1.x),
                                    fmaf(sres1, ww1.y, gg1.y + z1.y),
                                    fmaf(sres1, ww1.z, gg1.z + z1.z),
                                    fmaf(sres1, ww1.w, gg1.w + z1.w));
    }
}

extern "C" void kernel_launch(void* const* d_in, const int* in_sizes, int n_in,
                              void* d_out, int out_size, void* d_ws, size_t ws_size,
                              hipStream_t stream) {
    const float* x    = (const float*)d_in[0];
    const int*   ei   = (const int*)  d_in[1];
    const float* attr = (const float*)d_in[2];
    const float* Wl   = (const float*)d_in[3];
    const float* bl   = (const float*)d_in[4];
    const float* Wr   = (const float*)d_in[5];
    const float* br   = (const float*)d_in[6];
    const float* We   = (const float*)d_in[7];
    const float* att  = (const float*)d_in[8];
    const float* bias = (const float*)d_in[9];
    float* out = (float*)d_out;

    const int N = in_sizes[0];       // 50000
    const int E = in_sizes[2];       // 800000
    const int* src = ei;
    const int* dst = ei + E;

    const int nb = (N + BN - 1) / BN;   // 391 buckets of 128 nodes

    // workspace: sorted [nb*CAP]float4 (~19.2 MB) | gcur [nb]int
    char* w = (char*)d_ws;
    float4* sorted = (float4*)w;
    int*    gcur   = (int*)(w + (size_t)nb * CAP * 16);

    k_init<<<(nb + 255) / 256, 256, 0, stream>>>(gcur, nb);
    k_scatter<<<(E + EPB - 1) / EPB, 256, 0, stream>>>(src, dst, attr, x,
                                                       gcur, sorted, E, nb);
    k_node<<<nb, 1024, 0, stream>>>(x, gcur, sorted,
                                    Wl, Wr, We, bl, br, att, bias,
                                    (float4*)out, N);
}